// Round 12
// baseline (201.960 us; speedup 1.0000x reference)
//
#include <hip/hip_runtime.h>
#include <math.h>

// Problem constants (fixed by reference setup_inputs)
constexpr int B = 2, C = 16, H = 160, W = 192, S = 3, D = 48;
constexpr int HW = H * W;          // 30720 = 120 * 256
constexpr int SB = S * B;

// ------------------------------------------------------------------
// Setup kernel: per (s,b) fold projection chain into
//   A = Ks * R * inv(Kref) (3x3 f64), q = Ks * t (f64)
// so main kernel does p = depth*(A*[u,v,1]) + q.
// ws layout: (s*B+b)*12 doubles = [A row-major 0..8][q 9..11]
// ------------------------------------------------------------------
__global__ void precompute_mats(const float* __restrict__ ref_intr,
                                const float* __restrict__ src_intr,
                                const float* __restrict__ ref_to_src,
                                double* __restrict__ ws)
{
    const int i = threadIdx.x;
    if (i >= SB) return;
    const int b = i % B;

    const float* Kp = ref_intr + b * 9;
    const double a00 = Kp[0], a01 = Kp[1], a02 = Kp[2];
    const double a10 = Kp[3], a11 = Kp[4], a12 = Kp[5];
    const double a20 = Kp[6], a21 = Kp[7], a22 = Kp[8];
    const double c00 =  (a11 * a22 - a12 * a21);
    const double c01 = -(a10 * a22 - a12 * a20);
    const double c02 =  (a10 * a21 - a11 * a20);
    const double c10 = -(a01 * a22 - a02 * a21);
    const double c11 =  (a00 * a22 - a02 * a20);
    const double c12 = -(a00 * a21 - a01 * a20);
    const double c20 =  (a01 * a12 - a02 * a11);
    const double c21 = -(a00 * a12 - a02 * a10);
    const double c22 =  (a00 * a11 - a01 * a10);
    const double invdet = 1.0 / (a00 * c00 + a01 * c01 + a02 * c02);
    const double iK[9] = { c00 * invdet, c10 * invdet, c20 * invdet,
                           c01 * invdet, c11 * invdet, c21 * invdet,
                           c02 * invdet, c12 * invdet, c22 * invdet };

    const float* Tp = ref_to_src + i * 16;
    const float* Ks = src_intr + i * 9;

    double M[9];  // R * inv(K)
    #pragma unroll
    for (int r = 0; r < 3; ++r)
        #pragma unroll
        for (int c = 0; c < 3; ++c)
            M[r * 3 + c] = (double)Tp[r * 4 + 0] * iK[0 + c]
                         + (double)Tp[r * 4 + 1] * iK[3 + c]
                         + (double)Tp[r * 4 + 2] * iK[6 + c];

    double* o = ws + i * 12;
    #pragma unroll
    for (int r = 0; r < 3; ++r) {
        #pragma unroll
        for (int c = 0; c < 3; ++c)
            o[r * 3 + c] = (double)Ks[r * 3 + 0] * M[0 + c]
                         + (double)Ks[r * 3 + 1] * M[3 + c]
                         + (double)Ks[r * 3 + 2] * M[6 + c];
        o[9 + r] = (double)Ks[r * 3 + 0] * (double)Tp[3]
                 + (double)Ks[r * 3 + 1] * (double)Tp[7]
                 + (double)Ks[r * 3 + 2] * (double)Tp[11];
    }
}

// ------------------------------------------------------------------
// Main kernel. 2D grid (R4 win): blockIdx.y = b*D+d -> b/d/s wave-
// uniform, channel bases scalarize (saddr loads, SALU walks). NCHW
// stride-1 coalesced (R3 lesson). NO min-waves __launch_bounds__
// (R2/R5 HARD RULE: forced caps -> catastrophic scratch spills).
//
// Round-12: L1-THROUGHPUT-BOUND probe. Evidence: R6 (208 loads, more
// VALU) == R11 (256 loads, less VALU) within 2%; per-CU L1 service
// arithmetic (48.6k wave-loads x 4-5 cyc) covers 75-92% of measured
// duration; gfx94x-fallback VALUBusy appears ~2x inflated vs honest
// static issue count. => cut load instructions to the minimum:
// ONE merged channel loop for all 3 sources + fused ref stats
// = 13 loads/channel (1 rc + 12 taps) = 208/thread (-19% vs R11).
// rc loaded once serves stats AND all 3 dot products. All state in
// named scalars (rule #20). unroll 5 bounds the hoist window (~65
// loads, R11-like; R10's unroll-3 27-load window throttled MLP).
// Per-output arithmetic identical to R11 (same order) -> absmax same.
// If this lands 115-125us instead: kernel is issue-bound, revert R11.
// ------------------------------------------------------------------
__global__ __launch_bounds__(256) void plane_sweep_kernel(
    const float* __restrict__ ref_feats,   // [B,C,H,W]
    const float* __restrict__ src_feats,   // [S,B,C,H,W]
    const float* __restrict__ depths,      // [D]
    const double* __restrict__ mats,       // [SB][12]
    float* __restrict__ out)               // [B,D,H,W]
{
    const int pix = blockIdx.x * 256 + threadIdx.x;   // HW = 120*256 exact
    const int by  = blockIdx.y;                       // b*D + d (scalar)
    const int d   = by % D;                           // scalar
    const int b   = by / D;                           // scalar

    const int w = pix % W;
    const int h = pix / W;

    const double u = (double)w, v = (double)h;
    const double depth = (double)depths[d];    // scalar load

    // ---- phase 1: geometry for ALL 3 sources -> named scalars ----
    // (all f64 state dead after these three calls)
    auto geom = [&](const double* Aq,
                    float& w00, float& w01, float& w10, float& w11,
                    int& o00, int& o01, int& o10, int& o11) {
        const double rx = fma(u, Aq[0], fma(v, Aq[1], Aq[2]));
        const double ry = fma(u, Aq[3], fma(v, Aq[4], Aq[5]));
        const double rz = fma(u, Aq[6], fma(v, Aq[7], Aq[8]));

        const double p0 = fma(depth, rx, Aq[9]);
        const double p1 = fma(depth, ry, Aq[10]);
        const double p2 = fma(depth, rz, Aq[11]);

        const bool valid = p2 > 0.001;
        const double zs = fmax(p2, 0.001);
        // f64 reciprocal: v_rcp_f64 approx + 1 Newton step (>=2^-28 rel)
#if __has_builtin(__builtin_amdgcn_rcp)
        double r = __builtin_amdgcn_rcp(zs);
#else
        double r = (double)__builtin_amdgcn_rcpf((float)zs);
        r = r * fma(-zs, r, 2.0);
#endif
        r = r * fma(-zs, r, 2.0);
        const double x = p0 * r;
        const double y = p1 * r;

        const double x0f = floor(x);
        const double y0f = floor(y);
        // sub-pixel fractions -> f32 (f64 x,y already ~1e-12-accurate)
        const float fx = (float)(x - x0f);
        const float fy = (float)(y - y0f);
        const int x0 = (int)x0f;
        const int y0 = (int)y0f;
        const int x1 = x0 + 1;
        const int y1 = y0 + 1;

        const float gx = 1.0f - fx, gy = 1.0f - fy;
        const bool okx0 = (x0 >= 0) & (x0 < W);
        const bool okx1 = (x1 >= 0) & (x1 < W);
        const bool oky0 = (y0 >= 0) & (y0 < H);
        const bool oky1 = (y1 >= 0) & (y1 < H);
        w00 = (valid & okx0 & oky0) ? gx * gy : 0.0f;
        w01 = (valid & okx1 & oky0) ? fx * gy : 0.0f;
        w10 = (valid & okx0 & oky1) ? gx * fy : 0.0f;
        w11 = (valid & okx1 & oky1) ? fx * fy : 0.0f;

        const int x0c = min(max(x0, 0), W - 1);
        const int x1c = min(max(x1, 0), W - 1);
        const int y0c = min(max(y0, 0), H - 1);
        const int y1c = min(max(y1, 0), H - 1);
        o00 = y0c * W + x0c;
        o01 = y0c * W + x1c;
        o10 = y1c * W + x0c;
        o11 = y1c * W + x1c;
    };

    float wa00, wa01, wa10, wa11; int oa00, oa01, oa10, oa11;  // s=0
    float wb00, wb01, wb10, wb11; int ob00, ob01, ob10, ob11;  // s=1
    float wc00, wc01, wc10, wc11; int oc00, oc01, oc10, oc11;  // s=2
    geom(mats + (0 * B + b) * 12, wa00, wa01, wa10, wa11, oa00, oa01, oa10, oa11);
    geom(mats + (1 * B + b) * 12, wb00, wb01, wb10, wb11, ob00, ob01, ob10, ob11);
    geom(mats + (2 * B + b) * 12, wc00, wc01, wc10, wc11, oc00, oc01, oc10, oc11);

    // wave-uniform bases -> saddr loads; channel walks in SALU
    const float* rb  = ref_feats + (size_t)b * C * HW;
    const float* sb0 = src_feats + (size_t)(0 * B + b) * C * HW;
    const float* sb1 = src_feats + (size_t)(1 * B + b) * C * HW;
    const float* sb2 = src_feats + (size_t)(2 * B + b) * C * HW;

    // ---- phase 2: ONE merged channel loop (ref stats + 3 sources) ----
    // c = 0 peeled (compile-time shift init).
    float sum1, sqr1;
    float av0, st0 = 0.0f, s20 = 0.0f, rdot0;
    float av1, st1 = 0.0f, s21 = 0.0f, rdot1;
    float av2, st2 = 0.0f, s22 = 0.0f, rdot2;
    {
        const float rc = rb[pix];
        sum1 = rc;
        sqr1 = rc * rc;
        const float v0 = wa00 * sb0[oa00] + wa01 * sb0[oa01]
                       + wa10 * sb0[oa10] + wa11 * sb0[oa11];
        const float v1 = wb00 * sb1[ob00] + wb01 * sb1[ob01]
                       + wb10 * sb1[ob10] + wb11 * sb1[ob11];
        const float v2 = wc00 * sb2[oc00] + wc01 * sb2[oc01]
                       + wc10 * sb2[oc10] + wc11 * sb2[oc11];
        av0 = v0; av1 = v1; av2 = v2;
        rdot0 = rc * v0;
        rdot1 = rc * v1;
        rdot2 = rc * v2;
    }
    #pragma unroll 5   // 15 = 5*3; ~65-load hoist window (R11-like)
    for (int c = 1; c < C; ++c) {
        const float rc = rb[c * HW + pix];
        sum1 += rc;
        sqr1 = fmaf(rc, rc, sqr1);

        const float* p0 = sb0 + c * HW;
        const float* p1 = sb1 + c * HW;
        const float* p2 = sb2 + c * HW;
        const float val0 = wa00 * p0[oa00] + wa01 * p0[oa01]
                         + wa10 * p0[oa10] + wa11 * p0[oa11];
        const float val1 = wb00 * p1[ob00] + wb01 * p1[ob01]
                         + wb10 * p1[ob10] + wb11 * p1[ob11];
        const float val2 = wc00 * p2[oc00] + wc01 * p2[oc01]
                         + wc10 * p2[oc10] + wc11 * p2[oc11];

        const float t0 = val0 - av0;
        st0 += t0;
        s20 = fmaf(t0, t0, s20);
        rdot0 = fmaf(rc, val0, rdot0);

        const float t1 = val1 - av1;
        st1 += t1;
        s21 = fmaf(t1, t1, s21);
        rdot1 = fmaf(rc, val1, rdot1);

        const float t2 = val2 - av2;
        st2 += t2;
        s22 = fmaf(t2, t2, s22);
        rdot2 = fmaf(rc, val2, rdot2);
    }

    // ---- epilogue: ref stats folds + per-source NCC ----
    const float m1 = sum1 * (1.0f / C);
    float sq1 = fmaf(-sum1, m1, sqr1);     // Σ(r-m1)² = Σr² - sum1·m1
    sq1 = fmaxf(sq1, 0.0f);
    const float n1 = sqrtf(sq1);

    // Σval = st + C·av ; dot = Σrc·val - m1·Σval ;
    // Σ(f2-m2)² = s2 - st²/C (shifted form; clamp rounding negatives)
    float cost = 0.0f;
    {
        const float sv = fmaf((float)C, av0, st0);
        const float dot = fmaf(-m1, sv, rdot0);
        float sq2 = fmaf(-st0 * (1.0f / C), st0, s20);
        sq2 = fmaxf(sq2, 0.0f);
        cost += dot / (n1 * sqrtf(sq2) + 1e-6f);
    }
    {
        const float sv = fmaf((float)C, av1, st1);
        const float dot = fmaf(-m1, sv, rdot1);
        float sq2 = fmaf(-st1 * (1.0f / C), st1, s21);
        sq2 = fmaxf(sq2, 0.0f);
        cost += dot / (n1 * sqrtf(sq2) + 1e-6f);
    }
    {
        const float sv = fmaf((float)C, av2, st2);
        const float dot = fmaf(-m1, sv, rdot2);
        float sq2 = fmaf(-st2 * (1.0f / C), st2, s22);
        sq2 = fmaxf(sq2, 0.0f);
        cost += dot / (n1 * sqrtf(sq2) + 1e-6f);
    }

    // out base wave-uniform -> saddr store with voffset pix*4
    out[(size_t)by * HW + pix] = cost * (1.0f / S);
}

extern "C" void kernel_launch(void* const* d_in, const int* in_sizes, int n_in,
                              void* d_out, int out_size, void* d_ws, size_t ws_size,
                              hipStream_t stream) {
    const float* ref_feats  = (const float*)d_in[0];
    const float* src_feats  = (const float*)d_in[1];
    const float* ref_intr   = (const float*)d_in[2];
    const float* src_intr   = (const float*)d_in[3];
    const float* ref_to_src = (const float*)d_in[4];
    const float* depths     = (const float*)d_in[5];
    float* out = (float*)d_out;
    double* mats = (double*)d_ws;   // needs SB*12*8 = 576 bytes

    precompute_mats<<<1, 64, 0, stream>>>(ref_intr, src_intr, ref_to_src, mats);

    dim3 grid(HW / 256, B * D);     // 120 x 96, exact
    plane_sweep_kernel<<<grid, dim3(256), 0, stream>>>(
        ref_feats, src_feats, depths, mats, out);
}